// Round 6
// baseline (291.055 us; speedup 1.0000x reference)
//
#include <hip/hip_runtime.h>
#include <hip/hip_bf16.h>
#include <cstddef>

#define D_DIM 768
#define V_DIM 10240
#define ROWS 32768   // B*N = 8*4096
#define BM 128
#define BN 128
#define BK 32
#define KTILES (D_DIM / BK)   // 24
#define SZ (BM * BK)          // 4096 bf16 elems = 8 KB per buffer per matrix

using bf16x8 = __attribute__((ext_vector_type(8))) __bf16;
using f32x4  = __attribute__((ext_vector_type(4))) float;

// ---------------------------------------------------------------------------
// Pre-pass: fold permutation + 2*(x-0.5) affine into weights.
// W'[d][j] = 2 * W[d][perm(j)],  perm(j) = (j%3)*256 + (j/48)*16 + (j/3)%16
// bias[d]  = -sum_k W[d][k]
// ---------------------------------------------------------------------------
__global__ void prep_w(const float* __restrict__ W, __bf16* __restrict__ Wp,
                       float* __restrict__ bias) {
    __shared__ float row[D_DIM];
    __shared__ float red[256];
    const int d = blockIdx.x;
    const int t = threadIdx.x;
    float s = 0.f;
    for (int k = t; k < D_DIM; k += 256) {
        float w = W[(size_t)d * D_DIM + k];
        row[k] = w;
        s += w;
    }
    red[t] = s;
    __syncthreads();
    for (int off = 128; off > 0; off >>= 1) {
        if (t < off) red[t] += red[t + off];
        __syncthreads();
    }
    if (t == 0) bias[d] = -red[0];
    for (int j = t; j < D_DIM; j += 256) {
        int c  = j % 3;
        int pw = (j / 3) & 15;
        int ph = j / 48;
        Wp[(size_t)d * D_DIM + j] = (__bf16)(2.0f * row[c * 256 + ph * 16 + pw]);
    }
}

// ---------------------------------------------------------------------------
// Streaming prepass: x fp32 -> bf16 (8 elems/thread), fused aux outputs.
// ---------------------------------------------------------------------------
__global__ void conv_aux(const float* __restrict__ X, __bf16* __restrict__ Xb,
                         const int* __restrict__ coord, const int* __restrict__ valid,
                         float* __restrict__ out1, float* __restrict__ out2) {
    int i = blockIdx.x * blockDim.x + threadIdx.x;
    size_t base = (size_t)i * 8;
    const float4* src = (const float4*)(X + base);
    float4 f0 = src[0];
    float4 f1 = src[1];
    bf16x8 v;
    v[0] = (__bf16)f0.x; v[1] = (__bf16)f0.y; v[2] = (__bf16)f0.z; v[3] = (__bf16)f0.w;
    v[4] = (__bf16)f1.x; v[5] = (__bf16)f1.y; v[6] = (__bf16)f1.z; v[7] = (__bf16)f1.w;
    *(bf16x8*)(Xb + base) = v;

    if (i < ROWS) {
        int c0 = coord[2 * i];
        int c1 = coord[2 * i + 1];
        out1[2 * i]     = (float)c1;
        out1[2 * i + 1] = (float)c0;
        out2[i] = valid[i] ? 0.0f : 1.0f;
    }
}

// ---------------------------------------------------------------------------
// Aux-only kernel (fallback path when ws can't hold bf16 X).
// ---------------------------------------------------------------------------
__global__ void aux_out(const int* __restrict__ coord, const int* __restrict__ valid,
                        float* __restrict__ out1, float* __restrict__ out2) {
    int i = blockIdx.x * blockDim.x + threadIdx.x;
    if (i < ROWS) {
        int c0 = coord[2 * i];
        int c1 = coord[2 * i + 1];
        out1[2 * i]     = (float)c1;
        out1[2 * i + 1] = (float)c0;
        out2[i] = valid[i] ? 0.0f : 1.0f;
    }
}

// ---------------------------------------------------------------------------
// Fast GEMM (round-4 config + counted-vmcnt depth-2 pipeline):
//  - 3 LDS buffers (48 KB), prefetch 2 tiles ahead.
//  - Per step: vmcnt(4) [tile kt's 4 loads are the only ones older than
//    tile kt+1's 4 -> counted wait is exact] ; raw s_barrier ; issue
//    stage(kt+2) ; ds_read(cur) ; MFMA. Loads get 2 compute phases to land.
//  - Buffer reuse is race-free: buf written at iter kt was last read at
//    iter kt-1, and every wave's ds_reads complete (lgkmcnt before MFMA)
//    before it reaches the barrier separating the two.
//  - Swizzle + XCD grouping identical to round 4 (0 conflicts, 37 MB fetch).
// 128x128 tile, 4 waves (2x2 of 64x64), 16x16x32 bf16 MFMA, 4x4 acc.
// ---------------------------------------------------------------------------
__launch_bounds__(256)
__global__ void gemm_fast(const __bf16* __restrict__ Xb, const __bf16* __restrict__ Wp,
                          const float* __restrict__ bias, const float* __restrict__ ptab,
                          const int* __restrict__ coord, const int* __restrict__ valid,
                          float* __restrict__ out) {
    __shared__ __align__(16) __bf16 la[3 * SZ];
    __shared__ __align__(16) __bf16 lb[3 * SZ];

    // XCD-grouped block -> (panel, col) mapping. Grid = 1536 = 8 XCD x 192.
    const int id  = blockIdx.x;
    const int xcd = id & 7;
    const int j6  = id >> 3;           // 0..191
    const int p   = xcd * 32 + j6 / 6; // row panel 0..255
    const int c   = j6 % 6;            // col block 0..5
    const int m0  = p * BM;
    const int n0  = c * BN;

    const int tid  = threadIdx.x;
    const int lane = tid & 63;
    const int wave = tid >> 6;
    const int wr   = (wave >> 1) * 64;
    const int wc   = (wave & 1) * 64;
    const int lr   = lane & 15;
    const int qh   = lane >> 4;        // logical 16B k-unit (0..3)

    // Staging descriptors: two 16B units per thread per matrix.
    // Physical unit q = i*256+tid; row = q>>2, u_phys = q&3,
    // source logical unit = u_phys ^ ((row>>1)&3).
    const __bf16* srcA[2];
    const __bf16* srcB[2];
    int dst[2];
    #pragma unroll
    for (int i = 0; i < 2; ++i) {
        int q   = i * 256 + tid;
        int row = q >> 2;
        int un  = (q & 3) ^ ((row >> 1) & 3);
        srcA[i] = Xb + (size_t)(m0 + row) * D_DIM + un * 8;
        srcB[i] = Wp + (size_t)(n0 + row) * D_DIM + un * 8;
        dst[i]  = q * 8;     // linear LDS dest (bf16 elems), within a buffer
    }

    // Swizzled fragment read offsets (within a buffer).
    int aoff[4], boff[4];
    #pragma unroll
    for (int i = 0; i < 4; ++i) {
        int rowa = wr + i * 16 + lr;
        aoff[i] = rowa * BK + ((qh ^ ((rowa >> 1) & 3)) * 8);
        int rowb = wc + i * 16 + lr;
        boff[i] = rowb * BK + ((qh ^ ((rowb >> 1) & 3)) * 8);
    }

    f32x4 acc[4][4] = {};

#define STAGE(OFF, KT)                                                          \
    do {                                                                        \
        const int k0_ = (KT) * BK;                                              \
        _Pragma("unroll")                                                       \
        for (int i_ = 0; i_ < 2; ++i_) {                                        \
            __builtin_amdgcn_global_load_lds(                                   \
                (const __attribute__((address_space(1))) void*)(srcA[i_] + k0_),\
                (__attribute__((address_space(3))) void*)&la[(OFF) + dst[i_]],  \
                16, 0, 0);                                                      \
            __builtin_amdgcn_global_load_lds(                                   \
                (const __attribute__((address_space(1))) void*)(srcB[i_] + k0_),\
                (__attribute__((address_space(3))) void*)&lb[(OFF) + dst[i_]],  \
                16, 0, 0);                                                      \
        }                                                                       \
    } while (0)

#define COMPUTE(OFF)                                                            \
    do {                                                                        \
        bf16x8 af_[4], bf_[4];                                                  \
        _Pragma("unroll")                                                       \
        for (int i_ = 0; i_ < 4; ++i_) {                                        \
            af_[i_] = *(const bf16x8*)&la[(OFF) + aoff[i_]];                    \
            bf_[i_] = *(const bf16x8*)&lb[(OFF) + boff[i_]];                    \
        }                                                                       \
        _Pragma("unroll")                                                       \
        for (int i_ = 0; i_ < 4; ++i_)                                          \
            _Pragma("unroll")                                                   \
            for (int j_ = 0; j_ < 4; ++j_)                                      \
                acc[i_][j_] = __builtin_amdgcn_mfma_f32_16x16x32_bf16(          \
                    af_[i_], bf_[j_], acc[i_][j_], 0, 0, 0);                    \
    } while (0)

#define VMCNT4 asm volatile("s_waitcnt vmcnt(4)" ::: "memory")
#define VMCNT0 asm volatile("s_waitcnt vmcnt(0)" ::: "memory")
#define BAR    __builtin_amdgcn_s_barrier()

    // prologue: prefetch tiles 0 and 1
    STAGE(0, 0);
    STAGE(SZ, 1);

    // main loop: kt = 3t, 3t+1, 3t+2 for t = 0..6  (kt 0..20, stages 2..22)
    for (int t = 0; t < 7; ++t) {
        const int kb = 3 * t;
        VMCNT4; BAR; STAGE(2 * SZ, kb + 2); COMPUTE(0);
        VMCNT4; BAR; STAGE(0,      kb + 3); COMPUTE(SZ);
        VMCNT4; BAR; STAGE(SZ,     kb + 4); COMPUTE(2 * SZ);
    }
    // kt = 21: stage tile 23
    VMCNT4; BAR; STAGE(2 * SZ, 23); COMPUTE(0);
    // kt = 22
    VMCNT4; BAR; COMPUTE(SZ);
    // kt = 23
    VMCNT0; BAR; COMPUTE(2 * SZ);

#undef STAGE
#undef COMPUTE
#undef VMCNT4
#undef VMCNT0
#undef BAR

    const float* pt0 = ptab;
    const float* pt1 = ptab + (size_t)V_DIM * D_DIM;
    const int rq = (lane >> 4) * 4;

    float bvals[4];
    #pragma unroll
    for (int j = 0; j < 4; ++j)
        bvals[j] = bias[n0 + wc + j * 16 + lr];

    #pragma unroll
    for (int i = 0; i < 4; ++i) {
        #pragma unroll
        for (int r = 0; r < 4; ++r) {
            int m = m0 + wr + i * 16 + rq + r;
            int c0 = coord[2 * m];
            int c1 = coord[2 * m + 1];
            if (c0 < 0) c0 = 0;
            if (c1 < 0) c1 = 0;
            int vld = valid[m];
            #pragma unroll
            for (int j = 0; j < 4; ++j) {
                int d = n0 + wc + j * 16 + lr;
                float v = acc[i][j][r] + bvals[j];
                if (vld)
                    v += pt0[(size_t)c1 * D_DIM + d] + pt1[(size_t)c0 * D_DIM + d];
                out[(size_t)m * D_DIM + d] = v;
            }
        }
    }
}

// ---------------------------------------------------------------------------
// Fallback GEMM (fp32 X staged through registers) — round-0 structure, BK=32.
// ---------------------------------------------------------------------------
__launch_bounds__(256)
__global__ void gemm_slow(const float* __restrict__ X, const __bf16* __restrict__ Wp,
                          const float* __restrict__ bias, const float* __restrict__ ptab,
                          const int* __restrict__ coord, const int* __restrict__ valid,
                          float* __restrict__ out) {
    __shared__ __align__(16) __bf16 la[BM * BK];
    __shared__ __align__(16) __bf16 lb[BN * BK];

    const int n0 = blockIdx.x * BN;
    const int m0 = blockIdx.y * BM;

    const int tid  = threadIdx.x;
    const int lane = tid & 63;
    const int wave = tid >> 6;
    const int wr   = (wave >> 1) * 64;
    const int wc   = (wave & 1) * 64;
    const int lr   = lane & 15;
    const int kq   = (lane >> 4) * 8;

    f32x4 acc[4][4] = {};

    for (int kt = 0; kt < D_DIM / BK; ++kt) {
        const int k0 = kt * BK;

        #pragma unroll
        for (int i = 0; i < 2; ++i) {
            int idx = i * 2048 + tid * 8;
            int row = idx >> 5;
            int col = idx & 31;
            const __bf16* src = Wp + (size_t)(n0 + row) * D_DIM + k0 + col;
            __builtin_amdgcn_global_load_lds(
                (const __attribute__((address_space(1))) void*)src,
                (__attribute__((address_space(3))) void*)&lb[idx], 16, 0, 0);
        }

        #pragma unroll
        for (int i = 0; i < 2; ++i) {
            int idx = i * 2048 + tid * 8;
            int row = idx >> 5;
            int col = idx & 31;
            const float4* src = (const float4*)(X + (size_t)(m0 + row) * D_DIM + k0 + col);
            float4 f0 = src[0];
            float4 f1 = src[1];
            bf16x8 v;
            v[0] = (__bf16)f0.x; v[1] = (__bf16)f0.y; v[2] = (__bf16)f0.z; v[3] = (__bf16)f0.w;
            v[4] = (__bf16)f1.x; v[5] = (__bf16)f1.y; v[6] = (__bf16)f1.z; v[7] = (__bf16)f1.w;
            *(bf16x8*)&la[idx] = v;
        }

        __syncthreads();

        bf16x8 af[4], bfr[4];
        #pragma unroll
        for (int i = 0; i < 4; ++i)
            af[i] = *(const bf16x8*)&la[(wr + i * 16 + lr) * BK + kq];
        #pragma unroll
        for (int j = 0; j < 4; ++j)
            bfr[j] = *(const bf16x8*)&lb[(wc + j * 16 + lr) * BK + kq];

        #pragma unroll
        for (int i = 0; i < 4; ++i)
            #pragma unroll
            for (int j = 0; j < 4; ++j)
                acc[i][j] = __builtin_amdgcn_mfma_f32_16x16x32_bf16(af[i], bfr[j], acc[i][j], 0, 0, 0);

        __syncthreads();
    }

    const float* pt0 = ptab;
    const float* pt1 = ptab + (size_t)V_DIM * D_DIM;
    const int rq = (lane >> 4) * 4;

    float bvals[4];
    #pragma unroll
    for (int j = 0; j < 4; ++j)
        bvals[j] = bias[n0 + wc + j * 16 + lr];

    #pragma unroll
    for (int i = 0; i < 4; ++i) {
        #pragma unroll
        for (int r = 0; r < 4; ++r) {
            int m = m0 + wr + i * 16 + rq + r;
            int c0 = coord[2 * m];
            int c1 = coord[2 * m + 1];
            if (c0 < 0) c0 = 0;
            if (c1 < 0) c1 = 0;
            int vld = valid[m];
            #pragma unroll
            for (int j = 0; j < 4; ++j) {
                int d = n0 + wc + j * 16 + lr;
                float v = acc[i][j][r] + bvals[j];
                if (vld)
                    v += pt0[(size_t)c1 * D_DIM + d] + pt1[(size_t)c0 * D_DIM + d];
                out[(size_t)m * D_DIM + d] = v;
            }
        }
    }
}

extern "C" void kernel_launch(void* const* d_in, const int* in_sizes, int n_in,
                              void* d_out, int out_size, void* d_ws, size_t ws_size,
                              hipStream_t stream) {
    const float* x     = (const float*)d_in[0];
    const int*   coord = (const int*)d_in[1];
    const int*   valid = (const int*)d_in[2];
    const float* W     = (const float*)d_in[3];
    const float* ptab  = (const float*)d_in[4];

    float* out0 = (float*)d_out;                       // [32768][768]
    float* out1 = out0 + (size_t)ROWS * D_DIM;         // [32768][2]
    float* out2 = out1 + (size_t)ROWS * 2;             // [32768]

    // Workspace layout: [Xb bf16 48MB][Wp bf16 1.125MB][bias 3KB]
    const size_t xb_bytes = (size_t)ROWS * D_DIM * sizeof(__bf16);
    const size_t wp_bytes = (size_t)D_DIM * D_DIM * sizeof(__bf16);
    const size_t need = xb_bytes + wp_bytes + D_DIM * sizeof(float);

    if (ws_size >= need) {
        __bf16* Xb  = (__bf16*)d_ws;
        __bf16* Wp  = (__bf16*)((char*)d_ws + xb_bytes);
        float* bias = (float*)((char*)d_ws + xb_bytes + wp_bytes);

        hipLaunchKernelGGL(prep_w, dim3(D_DIM), dim3(256), 0, stream, W, Wp, bias);
        hipLaunchKernelGGL(conv_aux, dim3((ROWS * D_DIM / 8) / 256), dim3(256), 0, stream,
                           x, Xb, coord, valid, out1, out2);
        hipLaunchKernelGGL(gemm_fast, dim3((ROWS / BM) * (D_DIM / BN)), dim3(256), 0, stream,
                           Xb, Wp, bias, ptab, coord, valid, out0);
    } else {
        __bf16* Wp  = (__bf16*)d_ws;
        float* bias = (float*)((char*)d_ws + wp_bytes);

        hipLaunchKernelGGL(prep_w, dim3(D_DIM), dim3(256), 0, stream, W, Wp, bias);
        hipLaunchKernelGGL(aux_out, dim3(ROWS / 256), dim3(256), 0, stream, coord, valid, out1, out2);
        hipLaunchKernelGGL(gemm_slow, dim3(D_DIM / BN, ROWS / BM), dim3(256), 0, stream,
                           x, Wp, bias, ptab, coord, valid, out0);
    }
}

// Round 7
// 288.346 us; speedup vs baseline: 1.0094x; 1.0094x over previous
//
#include <hip/hip_runtime.h>
#include <hip/hip_bf16.h>
#include <cstddef>

#define D_DIM 768
#define V_DIM 10240
#define ROWS 32768   // B*N = 8*4096
#define BM 128
#define BN 128
#define BK 32

using bf16x8 = __attribute__((ext_vector_type(8))) __bf16;
using f32x4  = __attribute__((ext_vector_type(4))) float;

// ---------------------------------------------------------------------------
// Pre-pass: fold permutation + 2*(x-0.5) affine into weights.
// W'[d][j] = 2 * W[d][perm(j)],  perm(j) = (j%3)*256 + (j/48)*16 + (j/3)%16
// bias[d]  = -sum_k W[d][k]
// ---------------------------------------------------------------------------
__global__ void prep_w(const float* __restrict__ W, __bf16* __restrict__ Wp,
                       float* __restrict__ bias) {
    __shared__ float row[D_DIM];
    __shared__ float red[256];
    const int d = blockIdx.x;
    const int t = threadIdx.x;
    float s = 0.f;
    for (int k = t; k < D_DIM; k += 256) {
        float w = W[(size_t)d * D_DIM + k];
        row[k] = w;
        s += w;
    }
    red[t] = s;
    __syncthreads();
    for (int off = 128; off > 0; off >>= 1) {
        if (t < off) red[t] += red[t + off];
        __syncthreads();
    }
    if (t == 0) bias[d] = -red[0];
    for (int j = t; j < D_DIM; j += 256) {
        int c  = j % 3;
        int pw = (j / 3) & 15;
        int ph = j / 48;
        Wp[(size_t)d * D_DIM + j] = (__bf16)(2.0f * row[c * 256 + ph * 16 + pw]);
    }
}

// ---------------------------------------------------------------------------
// Fused GEMM (round-4 kernel + in-kernel fp32->bf16 A staging):
//  - Structure, tile, swizzle, XCD grouping, epilogue: IDENTICAL to round 4
//    (80.4 us, 0 bank conflicts, 37 MB fetch). Only the A path changes:
//    A is read as fp32 X (2x float4 per 16B unit), converted in-register,
//    ds_write_b128 to the swizzled LDS offset. conv_aux is deleted.
//  - B unchanged: global_load_lds w=16 with inverse-swizzled source.
//  - XCD grouping means the 6 col-blocks of a row panel replay the fp32 X
//    panel from the same XCD's L2; HBM reads X once (~100 MB).
//  - Aux outputs written by c==0 blocks in the prologue (rows exclusive).
// 128x128 tile, BK=32, 4 waves (2x2 of 64x64), 16x16x32 bf16 MFMA, 4x4 acc.
// ---------------------------------------------------------------------------
__launch_bounds__(256)
__global__ void gemm_fused(const float* __restrict__ X, const __bf16* __restrict__ Wp,
                           const float* __restrict__ bias, const float* __restrict__ ptab,
                           const int* __restrict__ coord, const int* __restrict__ valid,
                           float* __restrict__ out0, float* __restrict__ out1,
                           float* __restrict__ out2) {
    __shared__ __align__(16) __bf16 la[BM * BK];   // 8 KB
    __shared__ __align__(16) __bf16 lb[BN * BK];   // 8 KB

    // XCD-grouped block -> (panel, col) mapping. Grid = 1536 = 8 XCD x 192.
    const int id  = blockIdx.x;
    const int xcd = id & 7;
    const int j6  = id >> 3;           // 0..191
    const int p   = xcd * 32 + j6 / 6; // row panel 0..255
    const int c   = j6 % 6;            // col block 0..5
    const int m0  = p * BM;
    const int n0  = c * BN;

    const int tid  = threadIdx.x;
    const int lane = tid & 63;
    const int wave = tid >> 6;
    const int wr   = (wave >> 1) * 64;
    const int wc   = (wave & 1) * 64;
    const int lr   = lane & 15;
    const int qh   = lane >> 4;        // logical 16B k-unit (0..3)

    // Aux outputs: col-block 0 owns its 128 rows exclusively.
    if (c == 0 && tid < BM) {
        int m  = m0 + tid;
        int c0 = coord[2 * m];
        int c1 = coord[2 * m + 1];
        out1[2 * m]     = (float)c1;
        out1[2 * m + 1] = (float)c0;
        out2[m] = valid[m] ? 0.0f : 1.0f;
    }

    // Staging descriptors: two 16B units per thread per matrix.
    // Physical unit q = i*256+tid; row = q>>2, u_phys = q&3,
    // logical (source) unit = u_phys ^ ((row>>1)&3).
    // B: inverse-swizzled global source, linear LDS dest (gload_lds rule).
    // A: fp32 source at the LOGICAL unit, reg-staged ds_write to the
    //    physical (swizzled) LDS offset — same final layout as B.
    const float*  srcA[2];
    const __bf16* srcB[2];
    int dst[2];
    #pragma unroll
    for (int i = 0; i < 2; ++i) {
        int q   = i * 256 + tid;
        int row = q >> 2;
        int un  = (q & 3) ^ ((row >> 1) & 3);
        srcA[i] = X  + (size_t)(m0 + row) * D_DIM + un * 8;   // 8 floats
        srcB[i] = Wp + (size_t)(n0 + row) * D_DIM + un * 8;   // 8 bf16
        dst[i]  = q * 8;     // linear LDS dest (bf16 elems)
    }

    // Swizzled fragment read offsets.
    int aoff[4], boff[4];
    #pragma unroll
    for (int i = 0; i < 4; ++i) {
        int rowa = wr + i * 16 + lr;
        aoff[i] = rowa * BK + ((qh ^ ((rowa >> 1) & 3)) * 8);
        int rowb = wc + i * 16 + lr;
        boff[i] = rowb * BK + ((qh ^ ((rowb >> 1) & 3)) * 8);
    }

    f32x4 acc[4][4] = {};

    for (int kt = 0; kt < D_DIM / BK; ++kt) {
        const int k0 = kt * BK;

        // B: direct-to-LDS (latency overlaps the A chain below).
        #pragma unroll
        for (int i = 0; i < 2; ++i)
            __builtin_amdgcn_global_load_lds(
                (const __attribute__((address_space(1))) void*)(srcB[i] + k0),
                (__attribute__((address_space(3))) void*)&lb[dst[i]], 16, 0, 0);

        // A: fp32 -> bf16 in-register, one ds_write_b128 per unit.
        {
            float4 f00 = *(const float4*)(srcA[0] + k0);
            float4 f01 = *(const float4*)(srcA[0] + k0 + 4);
            float4 f10 = *(const float4*)(srcA[1] + k0);
            float4 f11 = *(const float4*)(srcA[1] + k0 + 4);
            bf16x8 v0, v1;
            v0[0] = (__bf16)f00.x; v0[1] = (__bf16)f00.y;
            v0[2] = (__bf16)f00.z; v0[3] = (__bf16)f00.w;
            v0[4] = (__bf16)f01.x; v0[5] = (__bf16)f01.y;
            v0[6] = (__bf16)f01.z; v0[7] = (__bf16)f01.w;
            v1[0] = (__bf16)f10.x; v1[1] = (__bf16)f10.y;
            v1[2] = (__bf16)f10.z; v1[3] = (__bf16)f10.w;
            v1[4] = (__bf16)f11.x; v1[5] = (__bf16)f11.y;
            v1[6] = (__bf16)f11.z; v1[7] = (__bf16)f11.w;
            *(bf16x8*)&la[dst[0]] = v0;
            *(bf16x8*)&la[dst[1]] = v1;
        }

        __syncthreads();

        bf16x8 af[4], bfr[4];
        #pragma unroll
        for (int i = 0; i < 4; ++i)
            af[i] = *(const bf16x8*)&la[aoff[i]];
        #pragma unroll
        for (int j = 0; j < 4; ++j)
            bfr[j] = *(const bf16x8*)&lb[boff[j]];

        #pragma unroll
        for (int i = 0; i < 4; ++i)
            #pragma unroll
            for (int j = 0; j < 4; ++j)
                acc[i][j] = __builtin_amdgcn_mfma_f32_16x16x32_bf16(af[i], bfr[j], acc[i][j], 0, 0, 0);

        __syncthreads();
    }

    const float* pt0 = ptab;
    const float* pt1 = ptab + (size_t)V_DIM * D_DIM;
    const int rq = (lane >> 4) * 4;

    float bvals[4];
    #pragma unroll
    for (int j = 0; j < 4; ++j)
        bvals[j] = bias[n0 + wc + j * 16 + lr];

    #pragma unroll
    for (int i = 0; i < 4; ++i) {
        #pragma unroll
        for (int r = 0; r < 4; ++r) {
            int m = m0 + wr + i * 16 + rq + r;
            int c0 = coord[2 * m];
            int c1 = coord[2 * m + 1];
            if (c0 < 0) c0 = 0;
            if (c1 < 0) c1 = 0;
            int vld = valid[m];
            #pragma unroll
            for (int j = 0; j < 4; ++j) {
                int d = n0 + wc + j * 16 + lr;
                float v = acc[i][j][r] + bvals[j];
                if (vld)
                    v += pt0[(size_t)c1 * D_DIM + d] + pt1[(size_t)c0 * D_DIM + d];
                out0[(size_t)m * D_DIM + d] = v;
            }
        }
    }
}

extern "C" void kernel_launch(void* const* d_in, const int* in_sizes, int n_in,
                              void* d_out, int out_size, void* d_ws, size_t ws_size,
                              hipStream_t stream) {
    const float* x     = (const float*)d_in[0];
    const int*   coord = (const int*)d_in[1];
    const int*   valid = (const int*)d_in[2];
    const float* W     = (const float*)d_in[3];
    const float* ptab  = (const float*)d_in[4];

    float* out0 = (float*)d_out;                       // [32768][768]
    float* out1 = out0 + (size_t)ROWS * D_DIM;         // [32768][2]
    float* out2 = out1 + (size_t)ROWS * 2;             // [32768]

    // Workspace: [Wp bf16 1.125 MB][bias 3 KB]
    __bf16* Wp   = (__bf16*)d_ws;
    float*  bias = (float*)((char*)d_ws + (size_t)D_DIM * D_DIM * sizeof(__bf16));

    hipLaunchKernelGGL(prep_w, dim3(D_DIM), dim3(256), 0, stream, W, Wp, bias);
    hipLaunchKernelGGL(gemm_fused, dim3((ROWS / BM) * (D_DIM / BN)), dim3(256), 0, stream,
                       x, Wp, bias, ptab, coord, valid, out0, out1, out2);
}